// Round 14
// baseline (6094.668 us; speedup 1.0000x reference)
//
#include <hip/hip_runtime.h>

#define NBATCH 64
#define NSEQ   32
#define NI     31
#define NC     16
#define NH     128
#define NW     256
#define NOUT   10
#define NSUB   62          // 31 intervals * 2 substeps

#define NGRP 8             // batch groups
#define GB   8             // batch rows per group
#define NSL  32            // slice blocks per group
#define NBLK (NGRP*NSL)    // 256 blocks = 1 per CU (LDS-forced)
#define BS   512

// per-slice weight ownership (fw1/fw2 only; fw0 is streamed full from L2)
#define L2R 8              // fw1 rows  (256/32)
#define L3H 4              // h-dims of fw2 (128/32)
#define L3R 64             // fw2 rows = L3H*16

// padded LDS strides (floats)
#define P128 132
#define P256 260

// workspace layout (bytes)
#define WS_BAR   0                       // 8 groups * 32 slots * 64B = 16 KB
#define WS_H2    16384                   // [8grp][32sl][8b][8r] f32 = 64 KB
#define WS_KV    (16384 + 65536)         // [8grp][6st][32sl][8b][4] f32 = 192 KB

typedef float f4v __attribute__((ext_vector_type(4)));

__device__ const float ATAB[6][5] = {
  {0.f, 0.f, 0.f, 0.f, 0.f},
  {0.161f, 0.f, 0.f, 0.f, 0.f},
  {-0.008480655492356989f, 0.335480655492357f, 0.f, 0.f, 0.f},
  {2.8971530571054935f, -6.359448489975075f, 4.3622954328695815f, 0.f, 0.f},
  {5.325864828439257f, -11.748883564062828f, 7.4955393428898365f, -0.09249506636175525f, 0.f},
  {5.86145544294642f, -12.92096931784711f, 8.159367898576159f, -0.071584973281401f, -0.028269050394068383f}
};
__device__ const float CNODE[6] = {0.f, 0.161f, 0.327f, 0.9f, 0.9800255409045097f, 1.f};
__device__ const float BTAB[6]  = {0.09646076681806523f, 0.01f, 0.4798896504144996f,
                                   1.379008574103742f, -3.290069515436081f, 2.324710524099774f};

__device__ __forceinline__ float softplusf_(float x) {
  return fmaxf(x, 0.0f) + log1pf(expf(-fabsf(x)));
}
__device__ __forceinline__ float dot4(float4 a, float4 b) {
  return (a.x*b.x + a.y*b.y) + (a.z*b.z + a.w*b.w);
}

// ---- device-coherent transport (agent scope; R4/R8-proven) ----
__device__ __forceinline__ void sta_f32(float* p, float v) {
  __hip_atomic_store(p, v, __ATOMIC_RELAXED, __HIP_MEMORY_SCOPE_AGENT);
}
__device__ __forceinline__ void sta_f32x4(float* p, f4v v) {
  asm volatile("global_store_dwordx4 %0, %1, off sc0 sc1" :: "v"(p), "v"(v) : "memory");
}
__device__ __forceinline__ f4v lda_f32x4(const float* p) {
  f4v r;
  asm volatile("global_load_dwordx4 %0, %1, off sc0 sc1\n\ts_waitcnt vmcnt(0)"
               : "=v"(r) : "v"(p) : "memory");
  return r;
}

// ---- barrier primitives (R4/R8-proven) ----
#define SLOT_STRIDE 16     // 64B per slot
__device__ __forceinline__ void bar_arrive(unsigned* slots, int myslot, unsigned seq) {
  asm volatile("s_waitcnt vmcnt(0)" ::: "memory");   // data stores acked at coherence point
  __syncthreads();                                   // all waves drained
  if (threadIdx.x == 0) {
    __hip_atomic_store(&slots[myslot * SLOT_STRIDE], seq,
                       __ATOMIC_RELAXED, __HIP_MEMORY_SCOPE_AGENT);
  }
}
__device__ __forceinline__ void bar_wait_wave(unsigned* slots, unsigned seq) {
  const int sl = threadIdx.x & 31;
  int guard = 0;
  for (;;) {
    const unsigned v = __hip_atomic_load(&slots[sl * SLOT_STRIDE],
                                         __ATOMIC_RELAXED, __HIP_MEMORY_SCOPE_AGENT);
    if (__all(v >= seq)) break;
    if (++guard > (1 << 22)) break;    // diagnostic escape, never a 600s timeout
    __builtin_amdgcn_s_sleep(1);
  }
}

__global__ void bar_init(unsigned* bar) {
  const int n = NGRP * NSL * SLOT_STRIDE;   // 4096
  for (int i = threadIdx.x; i < n; i += blockDim.x)
    __hip_atomic_store(&bar[i], 0u, __ATOMIC_RELAXED, __HIP_MEMORY_SCOPE_AGENT);
}

__global__ __launch_bounds__(BS) void ncde_fwd(
    const float* __restrict__ ts,
    const float* __restrict__ cd, const float* __restrict__ cc,
    const float* __restrict__ cb, const float* __restrict__ ca,
    const float* __restrict__ iw0, const float* __restrict__ ib0,
    const float* __restrict__ iw1, const float* __restrict__ ib1,
    const float* __restrict__ iw2, const float* __restrict__ ib2,
    const float* __restrict__ fw0, const float* __restrict__ fb0,
    const float* __restrict__ fw1, const float* __restrict__ fb1,
    const float* __restrict__ fw2, const float* __restrict__ fb2,
    const float* __restrict__ lw,  const float* __restrict__ lb,
    unsigned* __restrict__ bar, float* __restrict__ h2c,
    float* __restrict__ kvc, float* __restrict__ out)
{
  const int t   = threadIdx.x;
  const int g   = blockIdx.x & 7;         // group (XCD heuristic; correctness-independent)
  const int s   = blockIdx.x >> 3;        // slice 0..31
  const int gr0 = g * GB;
  unsigned* slots = bar + g * NSL * SLOT_STRIDE;
  unsigned  bseq  = 0;
  float* h2cg = h2c + g * (NSL*GB*L2R);   // [32][8][8]
  float* kvcg = kvc + g * (6*NSL*GB*4);   // [6][32][8][4]

  __shared__ float fw1s[L2R][P256];
  __shared__ float fw2s[L3R][P256];
  __shared__ float h1s[GB][NW];           // written locally by L1-full (no exchange)
  __shared__ float h2s[GB][NW];
  __shared__ float ysv[GB][P128];
  __shared__ float dxs[GB][NC];
  __shared__ float x0s[GB][NC];
  __shared__ float fb0s[NW];              // full fw0 bias
  __shared__ float fb1s[L2R], fb2s[L3R];
  __shared__ float tss[NSEQ];
  __shared__ float yfin[GB][NH];
  __shared__ float lgs[GB][NOUT], lses[GB];

  // ---- one-time: slice weights -> LDS; full fb0 -> LDS ----
  {
    {                                    // fw1: 8 rows x 64 f4 -> 1 f4/thread
      int r2 = t >> 6, j2 = t & 63;
      *(float4*)&fw1s[r2][4*j2] = *(const float4*)&fw1[(size_t)(s*L2R + r2)*NW + 4*j2];
    }
    #pragma unroll
    for (int i = 0; i < 8; ++i) {        // fw2: 64 rows x 64 f4 -> 8 f4/thread
      int e = t + BS*i; int r2 = e >> 6, j2 = e & 63;
      *(float4*)&fw2s[r2][4*j2] = *(const float4*)&fw2[(size_t)(s*L3R + r2)*NW + 4*j2];
    }
    if (t < NW)  fb0s[t] = fb0[t];
    if (t < L2R) fb1s[t] = fb1[s*L2R + t];
    if (t < L3R) fb2s[t] = fb2[s*L3R + t];
    if (t < NSEQ) tss[t] = ts[t];
  }

  // ---- init MLP (redundant per block, fully local) ----
  if (t < GB*NC) { int r = t >> 4, c = t & 15; x0s[r][c] = ca[((size_t)(gr0 + r)*NI)*NC + c]; }
  __syncthreads();
  #pragma unroll
  for (int i = 0; i < 4; ++i) {          // h1i
    int e = t + BS*i; int r = e >> 8, row = e & 255;
    float a = ib0[row];
    #pragma unroll
    for (int k = 0; k < NC; ++k) a += iw0[row*NC + k] * x0s[r][k];
    h1s[r][row] = fmaxf(a, 0.f);
  }
  __syncthreads();
  #pragma unroll
  for (int i = 0; i < 4; ++i) {          // h2i
    int e = t + BS*i; int r = e >> 8, row = e & 255;
    float a = ib1[row];
    const float4* wr = (const float4*)&iw1[(size_t)row*NW];
    for (int k = 0; k < 64; ++k) a += dot4(wr[k], *(const float4*)&h1s[r][4*k]);
    h2s[r][row] = fmaxf(a, 0.f);
  }
  __syncthreads();
  #pragma unroll
  for (int i = 0; i < 2; ++i) {          // y0
    int e = t + BS*i; int r = e >> 7, row = e & 127;
    float a = ib2[row];
    const float4* wr = (const float4*)&iw2[(size_t)row*NW];
    for (int k = 0; k < 64; ++k) a += dot4(wr[k], *(const float4*)&h2s[r][4*k]);
    yfin[r][row] = a;
  }
  __syncthreads();

  // ---- thread mappings ----
  const int lane = t & 63;
  const int w    = t >> 6;                      // wave index == batch row for L2/L3
  const int yr   = t >> 5, yc4 = 4*(t & 31);    // t<256: one y-f4 (batch yr, cols yc4..+3)
  const int o    = t >> 3, q8 = t & 7;          // L2: 8 threads per output
  const int orow = o & 7, obat = o >> 3;        // obat == w
  const int l3row = t & 63, l3c = t & 15, l3b = t >> 6;
  const int r1   = t & 255, half = t >> 8;      // L1-full: row r1, batches half*4..+3

  // ---- y and k stages live in registers (t<256) ----
  float4 yreg; f4v kreg[6];
  if (t < 256) yreg = *(const float4*)&yfin[yr][yc4];

  // ---- 62 Tsit5 substeps ----
  for (int ss = 0; ss < NSUB; ++ss) {
    const int iv = ss >> 1, jv = ss & 1;
    const float h = (tss[iv+1] - tss[iv]) * 0.5f;
    const float t0f = (float)jv * h;

    float cdv = 0.f, ccv = 0.f, cbv = 0.f;
    if (t >= 256 && t < 256 + GB*NC) {
      const int tc = t - 256;
      const size_t base = ((size_t)(gr0 + (tc >> 4))*NI + iv)*NC + (tc & 15);
      cdv = cd[base]; ccv = cc[base]; cbv = cb[base];
    }

    for (int st = 0; st < 6; ++st) {
      // ---- phase A: stage state from registers + dX/dt ----
      if (t < 256) {
        float4 v = yreg;
        for (int jj = 0; jj < st; ++jj) {
          const float a = h * ATAB[st][jj];
          v.x += a*kreg[jj][0]; v.y += a*kreg[jj][1];
          v.z += a*kreg[jj][2]; v.w += a*kreg[jj][3];
        }
        *(float4*)&ysv[yr][yc4] = v;
      } else if (t < 256 + GB*NC) {
        const int tc = t - 256;
        const float f = t0f + CNODE[st] * h;
        dxs[tc >> 4][tc & 15] = (3.f*cdv*f + 2.f*ccv)*f + cbv;
      }
      __syncthreads();

      // ---- L1-FULL (local, no exchange): thread = fw0 row r1 x 4 batches.
      // fw0 is read-only, identical across the XCD's 32 blocks -> L2-hot.
      {
        const float4* wr = (const float4*)&fw0[(size_t)r1 * NH];
        const int b0 = half * 4;
        float a0 = 0.f, a1 = 0.f, a2 = 0.f, a3 = 0.f;
        #pragma unroll 8
        for (int k = 0; k < 32; ++k) {
          const float4 wv = wr[k];
          a0 += dot4(wv, *(const float4*)&ysv[b0+0][4*k]);
          a1 += dot4(wv, *(const float4*)&ysv[b0+1][4*k]);
          a2 += dot4(wv, *(const float4*)&ysv[b0+2][4*k]);
          a3 += dot4(wv, *(const float4*)&ysv[b0+3][4*k]);
        }
        const float bb = fb0s[r1];
        h1s[b0+0][r1] = softplusf_(bb + a0);
        h1s[b0+1][r1] = softplusf_(bb + a1);
        h1s[b0+2][r1] = softplusf_(bb + a2);
        h1s[b0+3][r1] = softplusf_(bb + a3);
      }
      __syncthreads();

      // ---- L2 slice -> packed agent store ([slice][batch][row]) ----
      {
        float a0 = 0.f, a1 = 0.f;
        #pragma unroll
        for (int i = 0; i < 8; i += 2) {
          a0 += dot4(*(const float4*)&fw1s[orow][4*(q8+8*i)],     *(const float4*)&h1s[obat][4*(q8+8*i)]);
          a1 += dot4(*(const float4*)&fw1s[orow][4*(q8+8*(i+1))], *(const float4*)&h1s[obat][4*(q8+8*(i+1))]);
        }
        float a = a0 + a1;
        a += __shfl_xor(a, 1); a += __shfl_xor(a, 2); a += __shfl_xor(a, 4);
        const float praw = __shfl(a, (lane & 7) * 8);   // lane L -> row (L&7) of batch w
        if (lane < 8)
          sta_f32(&h2cg[(s*GB + w)*L2R + lane], softplusf_(fb1s[lane] + praw));
      }
      bar_arrive(slots, s, ++bseq);
      if (t < 64) bar_wait_wave(slots, bseq);
      __syncthreads();

      // consume full h2: one x4 agent load/thread, scatter to LDS
      {
        const f4v v = lda_f32x4(h2cg + 4*t);
        *(f4v*)&h2s[(t >> 1) & 7][(t >> 4)*8 + 4*(t & 1)] = v;
      }
      __syncthreads();

      // ---- L3: one fw2 row per thread -> one x4 store per wave ----
      {
        const float4* wr = (const float4*)&fw2s[l3row][0];
        const float4* xr = (const float4*)&h2s[l3b][0];
        float a0 = 0.f, a1 = 0.f, a2 = 0.f, a3 = 0.f;
        #pragma unroll 4
        for (int i = 0; i < 64; i += 4) {
          a0 += dot4(wr[i+0], xr[i+0]);
          a1 += dot4(wr[i+1], xr[i+1]);
          a2 += dot4(wr[i+2], xr[i+2]);
          a3 += dot4(wr[i+3], xr[i+3]);
        }
        float v0 = tanhf(((a0+a1)+(a2+a3)) + fb2s[l3row]) * dxs[l3b][l3c];
        v0 += __shfl_xor(v0, 1);
        v0 += __shfl_xor(v0, 2);
        v0 += __shfl_xor(v0, 4);
        v0 += __shfl_xor(v0, 8);
        f4v pk;
        pk[0] = __shfl(v0, 0);  pk[1] = __shfl(v0, 16);
        pk[2] = __shfl(v0, 32); pk[3] = __shfl(v0, 48);
        if (lane == 0)
          sta_f32x4(&kvcg[((st*NSL + s)*GB + w)*4], pk);
      }
      // kv: arrive; only consumer waves (t<256) wait + load; waves 4-7 run ahead
      bar_arrive(slots, s, ++bseq);
      if (t < 256) {
        bar_wait_wave(slots, bseq);
        kreg[st] = lda_f32x4(kvcg + ((st*NSL + (t & 31))*GB + yr)*4);
      }
    }

    // ---- y update in registers ----
    if (t < 256) {
      #pragma unroll
      for (int s2 = 0; s2 < 6; ++s2) {
        const float a = h * BTAB[s2];
        yreg.x += a*kreg[s2][0]; yreg.y += a*kreg[s2][1];
        yreg.z += a*kreg[s2][2]; yreg.w += a*kreg[s2][3];
      }
    }
  }

  // ---- write y back for readout ----
  if (t < 256) *(float4*)&yfin[yr][yc4] = yreg;
  __syncthreads();

  // ---- readout by slice 0 of each group ----
  if (s == 0) {
    if (t < GB*NOUT) {
      const int r = t / NOUT, oo = t % NOUT;
      float a = lb[oo];
      const float4* wr = (const float4*)&lw[(size_t)oo*NH];
      #pragma unroll
      for (int k = 0; k < 32; ++k) a += dot4(wr[k], *(const float4*)&yfin[r][4*k]);
      lgs[r][oo] = a;
    }
    __syncthreads();
    if (t < GB) {
      float m = lgs[t][0];
      for (int oo = 1; oo < NOUT; ++oo) m = fmaxf(m, lgs[t][oo]);
      float se = 0.f;
      for (int oo = 0; oo < NOUT; ++oo) se += expf(lgs[t][oo] - m);
      lses[t] = m + logf(se);
    }
    __syncthreads();
    if (t < GB*NOUT) {
      const int r = t / NOUT, oo = t % NOUT;
      out[(gr0 + r)*NOUT + oo] = lgs[r][oo] - lses[r];
    }
  }
}

extern "C" void kernel_launch(void* const* d_in, const int* in_sizes, int n_in,
                              void* d_out, int out_size, void* d_ws, size_t ws_size,
                              hipStream_t stream) {
  const float* ts  = (const float*)d_in[0];
  const float* cd  = (const float*)d_in[1];
  const float* cc  = (const float*)d_in[2];
  const float* cb  = (const float*)d_in[3];
  const float* ca  = (const float*)d_in[4];
  const float* iw0 = (const float*)d_in[5];
  const float* ib0 = (const float*)d_in[6];
  const float* iw1 = (const float*)d_in[7];
  const float* ib1 = (const float*)d_in[8];
  const float* iw2 = (const float*)d_in[9];
  const float* ib2 = (const float*)d_in[10];
  const float* fw0 = (const float*)d_in[11];
  const float* fb0 = (const float*)d_in[12];
  const float* fw1 = (const float*)d_in[13];
  const float* fb1 = (const float*)d_in[14];
  const float* fw2 = (const float*)d_in[15];
  const float* fb2 = (const float*)d_in[16];
  const float* lw  = (const float*)d_in[17];
  const float* lb  = (const float*)d_in[18];

  char* ws = (char*)d_ws;
  unsigned* bar = (unsigned*)(ws + WS_BAR);
  float* h2c = (float*)(ws + WS_H2);
  float* kvc = (float*)(ws + WS_KV);

  bar_init<<<1, 512, 0, stream>>>(bar);
  ncde_fwd<<<NBLK, BS, 0, stream>>>(ts, cd, cc, cb, ca, iw0, ib0, iw1, ib1, iw2, ib2,
                                    fw0, fb0, fw1, fb1, fw2, fb2, lw, lb,
                                    bar, h2c, kvc, (float*)d_out);
}